// Round 6
// baseline (406.556 us; speedup 1.0000x reference)
//
#include <hip/hip_runtime.h>

// ---------------- problem constants ----------------
#define B_     16
#define L_     1024
#define D_     768
#define C_     500
#define J_     10
#define M_     (B_ * L_)        // 16384
#define NREAL  (C_ * J_)        // 5000
#define NPAD   5120             // 20 * 256
#define TM     256
#define TN     256
#define TK     64
#define KTILES (D_ / TK)        // 12

typedef __attribute__((ext_vector_type(8))) short short8;
typedef __attribute__((ext_vector_type(16))) float f32x16;

// float <-> order-preserving uint (for atomicMax on signed floats)
static __device__ __forceinline__ unsigned f2ord(float f) {
    unsigned u = __float_as_uint(f);
    return (u & 0x80000000u) ? ~u : (u | 0x80000000u);
}
static __device__ __forceinline__ float ord2f(unsigned u) {
    return (u & 0x80000000u) ? __uint_as_float(u & 0x7fffffffu)
                             : __uint_as_float(~u);
}

// fp32 -> bf16 round-to-nearest-even
static __device__ __forceinline__ unsigned short f2bf(float f) {
    unsigned u = __float_as_uint(f);
    u += 0x7fffu + ((u >> 16) & 1u);
    return (unsigned short)(u >> 16);
}

// ---------------- kernel 1/2: L2-normalize rows fp32 -> bf16 ----------------
__global__ __launch_bounds__(256) void norm_rows_kernel(
    const float* __restrict__ in, unsigned short* __restrict__ out,
    int nrows, int valid_rows)
{
    int row  = blockIdx.x * 4 + (threadIdx.x >> 6);
    int lane = threadIdx.x & 63;
    if (row >= nrows) return;

    unsigned short* orow = out + (size_t)row * D_;
    if (row >= valid_rows) {               // zero pad rows
        ushort4 z = {0, 0, 0, 0};
        #pragma unroll
        for (int p = 0; p < 3; ++p)
            *(ushort4*)(orow + (p * 64 + lane) * 4) = z;
        return;
    }

    const float4* rp = (const float4*)(in + (size_t)row * D_);
    float4 v[3];
    float s = 0.f;
    #pragma unroll
    for (int p = 0; p < 3; ++p) {
        v[p] = rp[p * 64 + lane];
        s += v[p].x * v[p].x + v[p].y * v[p].y + v[p].z * v[p].z + v[p].w * v[p].w;
    }
    #pragma unroll
    for (int off = 32; off; off >>= 1) s += __shfl_xor(s, off);
    float inv = 1.f / fmaxf(sqrtf(s), 1e-12f);
    #pragma unroll
    for (int p = 0; p < 3; ++p) {
        ushort4 o;
        o.x = f2bf(v[p].x * inv);
        o.y = f2bf(v[p].y * inv);
        o.z = f2bf(v[p].z * inv);
        o.w = f2bf(v[p].w * inv);
        *(ushort4*)(orow + (p * 64 + lane) * 4) = o;
    }
}

// ---------------- kernel 3: 256x256 8-phase GEMM + fused max-over-L ----------------
// 8-phase template (T2 swizzle + T3/T4 counted vmcnt + T5 setprio), BK=64,
// 8 waves (2Mx4N), 128KiB LDS dbuf, MFMA 32x32x16 (2382 TF ceiling vs 2075
// for 16x16). Per wave: 4 m-tiles x 2 n-tiles of 32x32; B-frags (8)
// register-resident per K-tile; per phase: 4 A ds_reads + 2 staging loads +
// 8 MFMA. A/B operand layout: row = lane&31, k = (lane>>5)*8 + j.

#define MFMA32(a, b, c) __builtin_amdgcn_mfma_f32_32x32x16_bf16(a, b, c, 0, 0, 0)
#define FENCE asm volatile("" ::: "memory")
#define BAR   do { FENCE; __builtin_amdgcn_s_barrier(); FENCE; } while (0)
#define VM(N) asm volatile("s_waitcnt vmcnt(" #N ")" ::: "memory")
#define PRIO1 __builtin_amdgcn_s_setprio(1)
#define PRIO0 __builtin_amdgcn_s_setprio(0)

// read 4 A k-step frags for m-tile mt from buf p (offsets fold to imm)
#define RD_A4(dst, p, mt) do { \
    dst[0] = *(const short8*)(pA0 + (p)*32768 + (mt)*2048); \
    dst[1] = *(const short8*)(pA1 + (p)*32768 + (mt)*2048); \
    dst[2] = *(const short8*)(pA2 + (p)*32768 + (mt)*2048); \
    dst[3] = *(const short8*)(pA3 + (p)*32768 + (mt)*2048); \
} while (0)

// read all 8 B frags (2 n-tiles x 4 k-steps) from buf p
#define RD_B8(dst, p) do { \
    dst[0] = *(const short8*)(pB0 + (p)*32768); \
    dst[1] = *(const short8*)(pB1 + (p)*32768); \
    dst[2] = *(const short8*)(pB2 + (p)*32768); \
    dst[3] = *(const short8*)(pB3 + (p)*32768); \
    dst[4] = *(const short8*)(pB0 + (p)*32768 + 2048); \
    dst[5] = *(const short8*)(pB1 + (p)*32768 + 2048); \
    dst[6] = *(const short8*)(pB2 + (p)*32768 + 2048); \
    dst[7] = *(const short8*)(pB3 + (p)*32768 + 2048); \
} while (0)

// stage one 8KB quarter (q) of A/B for buf p at k-offset k0 (elements)
#define STAGE_A(p, q, k0) __builtin_amdgcn_global_load_lds( \
    (const __attribute__((address_space(1))) void*)(Z + gA0 + (q)*64*D_ + (unsigned)(k0)), \
    (__attribute__((address_space(3))) void*)(lds + (p)*32768 + (q)*4096 + tid8), 16, 0, 0)
#define STAGE_B(p, q, k0) __builtin_amdgcn_global_load_lds( \
    (const __attribute__((address_space(1))) void*)(Pm + gB0 + (q)*64*D_ + (unsigned)(k0)), \
    (__attribute__((address_space(3))) void*)(lds + (p)*32768 + 16384 + (q)*4096 + tid8), 16, 0, 0)

// one 8-MFMA cluster: m-tile mt x {n0,n1} x 4 k-steps
#define MM(mt, A4, Bv) do { \
    PRIO1; \
    _Pragma("unroll") \
    for (int ks_ = 0; ks_ < 4; ++ks_) { \
        acc[mt][0] = MFMA32(A4[ks_], Bv[ks_],   acc[mt][0]); \
        acc[mt][1] = MFMA32(A4[ks_], Bv[4+ks_], acc[mt][1]); \
    } \
    PRIO0; \
} while (0)

__global__ __launch_bounds__(512, 1) void gemm_maxpool_kernel(
    const unsigned short* __restrict__ Z,   // [M_][D_] bf16 bits
    const unsigned short* __restrict__ Pm,  // [NPAD][D_] bf16 bits
    unsigned int* __restrict__ pooled)      // [B_][NPAD] ord-encoded max
{
    __shared__ unsigned short lds[65536];   // 128 KiB: buf{0,1} x (A 32K | B 32K)

    const int tid  = threadIdx.x;
    const int lane = tid & 63;
    const int wid  = tid >> 6;              // 0..7
    const int wm   = wid >> 2;              // 0..1
    const int wn   = wid & 3;               // 0..3

    // XCD L2-chunked mapping: XCD x owns bm in [8x, 8x+8), bn-outer/bm-inner
    const int xcd = (int)blockIdx.x & 7;
    const int idx = (int)blockIdx.x >> 3;   // 0..159
    const int bm  = xcd * 8 + (idx & 7);    // 0..63
    const int bn  = idx >> 3;               // 0..19
    const int row0 = bm * TM;
    const int col0 = bn * TN;

    // ---- staging addresses (T2 swizzle on global source, linear LDS dest) ----
    const int tr    = tid >> 3;                                   // row within quarter
    const int tswz  = ((tid & 7) * 16) ^ ((tr & 7) << 4);         // swizzled col byte
    const int tid8  = tid * 8;                                    // shorts (16B/thread)
    const unsigned gA0 = (unsigned)(row0 + tr) * D_ + (tswz >> 1);
    const unsigned gB0 = (unsigned)(col0 + tr) * D_ + (tswz >> 1);

    // ---- ds_read fragment base pointers (swizzled); reads add imm offsets ----
    // A row = wm*128 + mt*32 + (lane&31); col byte = ks*32 + (lane>>5)*16,
    // swizzled by XOR ((row&7)<<4) = ((lane&7)<<4).
    const int l31  = lane & 31;
    const int hi16 = (lane >> 5) * 16;
    const int swzl = (lane & 7) << 4;
    const int cK0  = ((0 * 32 + hi16) ^ swzl) >> 1;   // shorts
    const int cK1  = ((1 * 32 + hi16) ^ swzl) >> 1;
    const int cK2  = ((2 * 32 + hi16) ^ swzl) >> 1;
    const int cK3  = ((3 * 32 + hi16) ^ swzl) >> 1;
    const unsigned short* pA0 = lds + (wm * 128 + l31) * 64 + cK0;
    const unsigned short* pA1 = lds + (wm * 128 + l31) * 64 + cK1;
    const unsigned short* pA2 = lds + (wm * 128 + l31) * 64 + cK2;
    const unsigned short* pA3 = lds + (wm * 128 + l31) * 64 + cK3;
    const unsigned short* pB0 = lds + 16384 + (wn * 64 + l31) * 64 + cK0;
    const unsigned short* pB1 = lds + 16384 + (wn * 64 + l31) * 64 + cK1;
    const unsigned short* pB2 = lds + 16384 + (wn * 64 + l31) * 64 + cK2;
    const unsigned short* pB3 = lds + 16384 + (wn * 64 + l31) * 64 + cK3;

    f32x16 acc[4][2] = {};
    short8 aC[4], bE[8], bO[8];

    // ---- prologue: stage tiles 0 (buf0) and 1 (buf1) ----
    STAGE_B(0,0,0);  STAGE_B(0,1,0);  STAGE_A(0,0,0);  STAGE_A(0,2,0);
    STAGE_B(0,2,0);  STAGE_B(0,3,0);  STAGE_A(0,1,0);  STAGE_A(0,3,0);
    STAGE_B(1,0,64); STAGE_B(1,1,64); STAGE_A(1,0,64); STAGE_A(1,2,64);
    STAGE_B(1,2,64); STAGE_B(1,3,64); STAGE_A(1,1,64); STAGE_A(1,3,64);
    VM(8);                      // tile0 landed; tile1 (8 loads) in flight
    BAR;
    RD_B8(bE, 0);               // tile0 B-all + A m-tile0
    RD_A4(aC, 0, 0);

    // ---- main loop: tiles 0..9, staging tiles 2..11 ----
    #pragma unroll 1
    for (int i = 0; i < 5; ++i) {
        const int kE = i * 128 + 128;   // k0 for tile 2i+2 (-> buf0)
        const int kO = i * 128 + 192;   // k0 for tile 2i+3 (-> buf1)
        short8 a1[4], a2[4], a3[4];

        // ===== even tile (buf0): aC/bE =====
        RD_A4(a1, 0, 1);  STAGE_B(0, 0, kE);  STAGE_B(0, 1, kE);
        BAR; MM(0, aC, bE); BAR;

        RD_A4(a2, 0, 2);  STAGE_A(0, 0, kE);  STAGE_A(0, 2, kE);
        BAR; MM(1, a1, bE); BAR;

        RD_A4(a3, 0, 3);  STAGE_B(0, 2, kE);  STAGE_B(0, 3, kE);
        VM(6);                      // drain odd tile's 8; leave 6 in flight
        BAR; MM(2, a2, bE); BAR;

        STAGE_A(0, 1, kE);  STAGE_A(0, 3, kE);
        MM(3, a3, bE);
        RD_B8(bO, 1);  RD_A4(aC, 1, 0);         // next (odd) tile frags
        BAR;

        // ===== odd tile (buf1): aC/bO =====
        RD_A4(a1, 1, 1);  STAGE_B(1, 0, kO);  STAGE_B(1, 1, kO);
        BAR; MM(0, aC, bO); BAR;

        RD_A4(a2, 1, 2);  STAGE_A(1, 0, kO);  STAGE_A(1, 2, kO);
        BAR; MM(1, a1, bO); BAR;

        RD_A4(a3, 1, 3);  STAGE_B(1, 2, kO);  STAGE_B(1, 3, kO);
        VM(6);                      // drain even tile (2i+2)'s 8
        BAR; MM(2, a2, bO); BAR;

        STAGE_A(1, 1, kO);  STAGE_A(1, 3, kO);
        MM(3, a3, bO);
        RD_B8(bE, 0);  RD_A4(aC, 0, 0);         // tile 2i+2 frags
        BAR;
    }

    // ===== epilogue tile 10 (buf0), no staging =====
    {
        short8 a1[4], a2[4], a3[4];
        RD_A4(a1, 0, 1);
        BAR; MM(0, aC, bE); BAR;
        RD_A4(a2, 0, 2);
        BAR; MM(1, a1, bE); BAR;
        RD_A4(a3, 0, 3);
        VM(0);                      // drain tile 11's 8 loads
        BAR; MM(2, a2, bE); BAR;
        MM(3, a3, bE);
        RD_B8(bO, 1);  RD_A4(aC, 1, 0);
        BAR;

        // ===== epilogue tile 11 (buf1) =====
        RD_A4(a1, 1, 1);
        BAR; MM(0, aC, bO); BAR;
        RD_A4(a2, 1, 2);
        BAR; MM(1, a1, bO); BAR;
        RD_A4(a3, 1, 3);
        BAR; MM(2, a2, bO); BAR;
        MM(3, a3, bO);
    }

    // ---- fused max-pool epilogue ----
    // C/D layout (32x32): col = lane&31, row = (reg&3)+8*(reg>>2)+4*(lane>>5)
    const int batch = row0 >> 10;           // 256 | 1024
    #pragma unroll
    for (int ni = 0; ni < 2; ++ni) {
        float v = -3.0e38f;
        #pragma unroll
        for (int mt = 0; mt < 4; ++mt)
            #pragma unroll
            for (int r = 0; r < 16; ++r)
                v = fmaxf(v, acc[mt][ni][r]);
        v = fmaxf(v, __shfl_xor(v, 32));    // merge lane>>5 halves
        if (lane < 32) {
            int col = col0 + wn * 64 + ni * 32 + l31;
            atomicMax(&pooled[(size_t)batch * NPAD + col], f2ord(v));
        }
    }
}

// ---------------- kernel 4: finalize logits ----------------
__global__ __launch_bounds__(256) void finalize_kernel(
    const unsigned int* __restrict__ pooled,  // [B_][NPAD]
    const float* __restrict__ rw,             // [C_][J_]
    const float* __restrict__ bias,           // [C_]
    float* __restrict__ out)                  // [B_][C_]
{
    int t = blockIdx.x * 256 + threadIdx.x;
    if (t >= B_ * C_) return;
    int b = t / C_, c = t % C_;
    float s = 0.f;
    #pragma unroll
    for (int j = 0; j < J_; ++j) {
        float pv = ord2f(pooled[(size_t)b * NPAD + c * J_ + j]);
        float x  = rw[c * J_ + j];
        float w  = fmaxf(x, 0.f) + log1pf(expf(-fabsf(x)));  // softplus
        s += pv * w;
    }
    out[t] = s + bias[c];
}

// ---------------- launch ----------------
extern "C" void kernel_launch(void* const* d_in, const int* in_sizes, int n_in,
                              void* d_out, int out_size, void* d_ws, size_t ws_size,
                              hipStream_t stream) {
    const float* spatial = (const float*)d_in[0];   // (16,1024,768)
    const float* protos  = (const float*)d_in[1];   // (500,10,768)
    const float* rw      = (const float*)d_in[2];   // (500,10)
    const float* bias    = (const float*)d_in[3];   // (500,)
    float* out = (float*)d_out;                     // (16,500)

    unsigned short* z = (unsigned short*)d_ws;                     // 16384*768 bf16
    unsigned short* p = z + (size_t)M_ * D_;                       // 5120*768 bf16
    unsigned int* pooled = (unsigned int*)(p + (size_t)NPAD * D_); // 16*5120 u32

    norm_rows_kernel<<<M_ / 4, 256, 0, stream>>>(spatial, z, M_, M_);
    norm_rows_kernel<<<NPAD / 4, 256, 0, stream>>>(protos, p, NPAD, NREAL);
    hipMemsetAsync(pooled, 0, (size_t)B_ * NPAD * sizeof(unsigned int), stream);
    gemm_maxpool_kernel<<<(M_ / TM) * (NPAD / TN), 512, 0, stream>>>(z, p, pooled);
    finalize_kernel<<<(B_ * C_ + 255) / 256, 256, 0, stream>>>(pooled, rw, bias, out);
}

// Round 7
// 125.115 us; speedup vs baseline: 3.2495x; 3.2495x over previous
//
#include <hip/hip_runtime.h>

// ---------------- problem constants ----------------
#define B_     16
#define L_     1024
#define D_     768
#define C_     500
#define J_     10
#define M_     (B_ * L_)        // 16384
#define NREAL  (C_ * J_)        // 5000
#define NPAD   5120             // 20 * 256
#define TM     256
#define TN     256
#define TK     64
#define KTILES (D_ / TK)        // 12
#define DCOL   ((unsigned)TN * D_)   // B-base advance per output tile

typedef __attribute__((ext_vector_type(8))) short short8;
typedef __attribute__((ext_vector_type(4))) float f32x4;

struct frag2 { short8 k[2]; };

// float <-> order-preserving uint (for atomicMax on signed floats)
static __device__ __forceinline__ unsigned f2ord(float f) {
    unsigned u = __float_as_uint(f);
    return (u & 0x80000000u) ? ~u : (u | 0x80000000u);
}
static __device__ __forceinline__ float ord2f(unsigned u) {
    return (u & 0x80000000u) ? __uint_as_float(u & 0x7fffffffu)
                             : __uint_as_float(~u);
}

// fp32 -> bf16 round-to-nearest-even
static __device__ __forceinline__ unsigned short f2bf(float f) {
    unsigned u = __float_as_uint(f);
    u += 0x7fffu + ((u >> 16) & 1u);
    return (unsigned short)(u >> 16);
}

// ---------------- kernel 1: prep = normalize both inputs + zero pooled ----------------
// blocks [0,4096): spatial rows; [4096,5376): proto rows (pad rows zeroed);
// blocks [0,80) additionally zero the pooled buffer (80*256*4 u32 = 81920).
__global__ __launch_bounds__(256) void prep_kernel(
    const float* __restrict__ spatial, const float* __restrict__ protos,
    unsigned short* __restrict__ z, unsigned short* __restrict__ pbuf,
    unsigned int* __restrict__ pooled)
{
    const int bid = blockIdx.x;
    if (bid < 80) {
        uint4 zz = {0, 0, 0, 0};
        *(uint4*)(pooled + bid * 1024 + threadIdx.x * 4) = zz;
    }

    const float* in;
    unsigned short* out;
    int row, valid;
    if (bid < 4096) { in = spatial; out = z;    row = bid * 4 + (threadIdx.x >> 6);          valid = M_; }
    else            { in = protos;  out = pbuf; row = (bid - 4096) * 4 + (threadIdx.x >> 6); valid = NREAL; }
    const int lane = threadIdx.x & 63;

    unsigned short* orow = out + (size_t)row * D_;
    if (row >= valid) {                    // zero pad rows (protos only)
        ushort4 zz = {0, 0, 0, 0};
        #pragma unroll
        for (int p = 0; p < 3; ++p)
            *(ushort4*)(orow + (p * 64 + lane) * 4) = zz;
        return;
    }

    const float4* rp = (const float4*)(in + (size_t)row * D_);
    float4 v[3];
    float s = 0.f;
    #pragma unroll
    for (int p = 0; p < 3; ++p) {
        v[p] = rp[p * 64 + lane];
        s += v[p].x * v[p].x + v[p].y * v[p].y + v[p].z * v[p].z + v[p].w * v[p].w;
    }
    #pragma unroll
    for (int off = 32; off; off >>= 1) s += __shfl_xor(s, off);
    float inv = 1.f / fmaxf(sqrtf(s), 1e-12f);
    #pragma unroll
    for (int p = 0; p < 3; ++p) {
        ushort4 o;
        o.x = f2bf(v[p].x * inv);
        o.y = f2bf(v[p].y * inv);
        o.z = f2bf(v[p].z * inv);
        o.w = f2bf(v[p].w * inv);
        *(ushort4*)(orow + (p * 64 + lane) * 4) = o;
    }
}

// ---------------- kernel 2: persistent 256x256 8-phase GEMM + fused max-over-L ----
// Round-5 verified schedule (T2 swizzle + counted vmcnt + setprio, 16x16x32),
// now persistent: 256 blocks (1/CU), fixed bm per block, 5 bn tiles chained.
// Pair i=5 computes K-tiles 10,11 while staging next output tile's K-tiles 0,1
// (A base unchanged, B base +DCOL) -> one pipeline fill per block, not 5.

#define MFMA(a, b, c) __builtin_amdgcn_mfma_f32_16x16x32_bf16(a, b, c, 0, 0, 0)
#define FENCE asm volatile("" ::: "memory")
#define BAR   do { FENCE; __builtin_amdgcn_s_barrier(); FENCE; } while (0)
#define VM(N) asm volatile("s_waitcnt vmcnt(" #N ")" ::: "memory")
#define PRIO1 __builtin_amdgcn_s_setprio(1)
#define PRIO0 __builtin_amdgcn_s_setprio(0)

// read a-frag pair (mi, mi+1), both kk, from buf p (offsets fold into ds imm)
#define RD_A2(dst, p, mi) do { \
    dst[0].k[0] = *(const short8*)(bA0 + (p)*32768 + (mi)*1024); \
    dst[0].k[1] = *(const short8*)(bA1 + (p)*32768 + (mi)*1024); \
    dst[1].k[0] = *(const short8*)(bA0 + (p)*32768 + ((mi)+1)*1024); \
    dst[1].k[1] = *(const short8*)(bA1 + (p)*32768 + ((mi)+1)*1024); \
} while (0)

// read all 4 b-frags, both kk, from buf p
#define RD_B4(dst, p) do { \
    _Pragma("unroll") \
    for (int ni_ = 0; ni_ < 4; ++ni_) { \
        dst[ni_].k[0] = *(const short8*)(bB0 + (p)*32768 + ni_*1024); \
        dst[ni_].k[1] = *(const short8*)(bB1 + (p)*32768 + ni_*1024); \
    } \
} while (0)

// stage one 8KB quarter (q) of A/B for buf p at k-offset k0 (elements)
#define STAGE_A(p, q, k0) __builtin_amdgcn_global_load_lds( \
    (const __attribute__((address_space(1))) void*)(Z + gA0 + (q)*64*D_ + (unsigned)(k0)), \
    (__attribute__((address_space(3))) void*)(lds + (p)*32768 + (q)*4096 + tid8), 16, 0, 0)
#define STAGE_B(p, q, k0, GB) __builtin_amdgcn_global_load_lds( \
    (const __attribute__((address_space(1))) void*)(Pm + (GB) + (q)*64*D_ + (unsigned)(k0)), \
    (__attribute__((address_space(3))) void*)(lds + (p)*32768 + 16384 + (q)*4096 + tid8), 16, 0, 0)

// one 16-MFMA cluster: C rows 2j,2j+1 x ni 0..3 x kk 0,1
#define MMPAIR(j, S, Bv) do { \
    PRIO1; \
    _Pragma("unroll") \
    for (int ni_ = 0; ni_ < 4; ++ni_) { \
        acc[2*(j)][ni_]   = MFMA(S[0].k[0], Bv[ni_].k[0], acc[2*(j)][ni_]); \
        acc[2*(j)+1][ni_] = MFMA(S[1].k[0], Bv[ni_].k[0], acc[2*(j)+1][ni_]); \
        acc[2*(j)][ni_]   = MFMA(S[0].k[1], Bv[ni_].k[1], acc[2*(j)][ni_]); \
        acc[2*(j)+1][ni_] = MFMA(S[1].k[1], Bv[ni_].k[1], acc[2*(j)+1][ni_]); \
    } \
    PRIO0; \
} while (0)

__global__ __launch_bounds__(512, 1) void gemm_maxpool_kernel(
    const unsigned short* __restrict__ Z,   // [M_][D_] bf16 bits
    const unsigned short* __restrict__ Pm,  // [NPAD][D_] bf16 bits
    unsigned int* __restrict__ pooled)      // [B_][NPAD] ord-encoded max
{
    __shared__ unsigned short lds[65536];   // 128 KiB: buf{0,1} x (A 32K | B 32K)

    const int tid  = threadIdx.x;
    const int lane = tid & 63;
    const int wid  = tid >> 6;              // 0..7
    const int wm   = wid >> 2;              // 0..1
    const int wn   = wid & 3;               // 0..3

    // persistent mapping: XCD x owns bm in [8x,8x+8); 4 bn-groups of 5 tiles
    const int xcd = (int)blockIdx.x & 7;
    const int lb  = (int)blockIdx.x >> 3;   // 0..31
    const int bm  = xcd * 8 + (lb & 7);     // 0..63
    const int bng = lb >> 3;                // 0..3
    const int row0 = bm * TM;
    int col0 = bng * 5 * TN;                // advances by TN per tile

    // ---- staging addresses (T2 swizzle on global source, linear LDS dest) ----
    const int tr    = tid >> 3;                                   // row within quarter
    const int tswz  = ((tid & 7) * 16) ^ ((tr & 7) << 4);         // swizzled col byte
    const int tid8  = tid * 8;                                    // shorts (16B/thread)
    const unsigned gA0 = (unsigned)(row0 + tr) * D_ + (tswz >> 1);
    unsigned gBc = (unsigned)(col0 + tr) * D_ + (tswz >> 1);

    // ---- ds_read fragment base pointers (swizzled); reads add imm offsets ----
    const int l15   = lane & 15;
    const int swzl  = (lane & 7) << 4;
    const int colS0 = ((((lane >> 4) * 16)      ) ^ swzl) >> 1;
    const int colS1 = ((((lane >> 4) * 16) + 64 ) ^ swzl) >> 1;
    const unsigned short* bA0 = lds + (wm * 128 + l15) * 64 + colS0;
    const unsigned short* bA1 = lds + (wm * 128 + l15) * 64 + colS1;
    const unsigned short* bB0 = lds + 16384 + (wn * 64 + l15) * 64 + colS0;
    const unsigned short* bB1 = lds + 16384 + (wn * 64 + l15) * 64 + colS1;

    f32x4 acc[8][4] = {};
    frag2 aE[2], aO[2], bE[4], bO[4];

    // ---- prologue: stage K-tiles 0 (buf0) and 1 (buf1) of output tile 0 ----
    STAGE_B(0,0,0,gBc);  STAGE_B(0,1,0,gBc);  STAGE_A(0,0,0);  STAGE_A(0,2,0);
    STAGE_B(0,2,0,gBc);  STAGE_B(0,3,0,gBc);  STAGE_A(0,1,0);  STAGE_A(0,3,0);
    STAGE_B(1,0,64,gBc); STAGE_B(1,1,64,gBc); STAGE_A(1,0,64); STAGE_A(1,2,64);
    STAGE_B(1,2,64,gBc); STAGE_B(1,3,64,gBc); STAGE_A(1,1,64); STAGE_A(1,3,64);
    VM(8);                      // K-tile0 landed; K-tile1 (8 loads) in flight
    BAR;
    RD_B4(bE, 0);
    RD_A2(aE, 0, 0);

    // ---- persistent loop over 5 output tiles ----
    #pragma unroll 1
    for (int t = 0; t < 5; ++t) {
        const unsigned gBn = (t < 4) ? gBc + DCOL : gBc;  // next tile's B base (wrap: restage self)

        #pragma unroll 1
        for (int i = 0; i < 6; ++i) {
            const int wrap = (i == 5);
            const unsigned bB = wrap ? gBn : gBc;
            const unsigned kE = wrap ? 0u  : (unsigned)(i * 128 + 128);  // K-tile 2i+2
            const unsigned kO = wrap ? 64u : (unsigned)(i * 128 + 192);  // K-tile 2i+3
            frag2 t23[2], t45[2], t67[2];

            // ===== even K-tile (buf0): aE/bE =====
            RD_A2(t23, 0, 2);  STAGE_B(0, 0, kE, bB);  STAGE_B(0, 1, kE, bB);
            BAR; MMPAIR(0, aE, bE); BAR;

            RD_A2(t45, 0, 4);  STAGE_A(0, 0, kE);  STAGE_A(0, 2, kE);
            BAR; MMPAIR(1, t23, bE); BAR;

            RD_A2(t67, 0, 6);  STAGE_B(0, 2, kE, bB);  STAGE_B(0, 3, kE, bB);
            VM(6);                      // drain odd K-tile's 8; leave 6 in flight
            BAR; MMPAIR(2, t45, bE); BAR;

            STAGE_A(0, 1, kE);  STAGE_A(0, 3, kE);
            MMPAIR(3, t67, bE);
            RD_B4(bO, 1);  RD_A2(aO, 1, 0);         // next (odd) K-tile frags
            BAR;

            // ===== odd K-tile (buf1): aO/bO =====
            RD_A2(t23, 1, 2);  STAGE_B(1, 0, kO, bB);  STAGE_B(1, 1, kO, bB);
            BAR; MMPAIR(0, aO, bO); BAR;

            RD_A2(t45, 1, 4);  STAGE_A(1, 0, kO);  STAGE_A(1, 2, kO);
            BAR; MMPAIR(1, t23, bO); BAR;

            RD_A2(t67, 1, 6);  STAGE_B(1, 2, kO, bB);  STAGE_B(1, 3, kO, bB);
            VM(6);                      // drain even K-tile's 8
            BAR; MMPAIR(2, t45, bO); BAR;

            STAGE_A(1, 1, kO);  STAGE_A(1, 3, kO);
            MMPAIR(3, t67, bO);
            RD_B4(bE, 0);  RD_A2(aE, 0, 0);         // next even K-tile frags
            BAR;
        }

        // ---- per-tile fused max-pool epilogue + acc reset ----
        // C/D layout: col = lane&15, row = (lane>>4)*4 + reg
        const int batch = row0 >> 10;           // 256 | 1024
        #pragma unroll
        for (int ni = 0; ni < 4; ++ni) {
            float v = -3.0e38f;
            #pragma unroll
            for (int mi = 0; mi < 8; ++mi)
                v = fmaxf(v, fmaxf(fmaxf(acc[mi][ni][0], acc[mi][ni][1]),
                                   fmaxf(acc[mi][ni][2], acc[mi][ni][3])));
            v = fmaxf(v, __shfl_xor(v, 16));
            v = fmaxf(v, __shfl_xor(v, 32));
            if (lane < 16) {
                int col = col0 + wn * 64 + ni * 16 + lane;
                atomicMax(&pooled[(size_t)batch * NPAD + col], f2ord(v));
            }
        }
        #pragma unroll
        for (int mi = 0; mi < 8; ++mi)
            #pragma unroll
            for (int ni = 0; ni < 4; ++ni)
                acc[mi][ni] = (f32x4){0.f, 0.f, 0.f, 0.f};

        gBc = gBn;
        col0 += TN;
    }

    VM(0);   // drain wrap-staged loads before workgroup teardown
}

// ---------------- kernel 3: finalize logits ----------------
__global__ __launch_bounds__(256) void finalize_kernel(
    const unsigned int* __restrict__ pooled,  // [B_][NPAD]
    const float* __restrict__ rw,             // [C_][J_]
    const float* __restrict__ bias,           // [C_]
    float* __restrict__ out)                  // [B_][C_]
{
    int t = blockIdx.x * 256 + threadIdx.x;
    if (t >= B_ * C_) return;
    int b = t / C_, c = t % C_;
    float s = 0.f;
    #pragma unroll
    for (int j = 0; j < J_; ++j) {
        float pv = ord2f(pooled[(size_t)b * NPAD + c * J_ + j]);
        float x  = rw[c * J_ + j];
        float w  = fmaxf(x, 0.f) + log1pf(expf(-fabsf(x)));  // softplus
        s += pv * w;
    }
    out[t] = s + bias[c];
}

// ---------------- launch ----------------
extern "C" void kernel_launch(void* const* d_in, const int* in_sizes, int n_in,
                              void* d_out, int out_size, void* d_ws, size_t ws_size,
                              hipStream_t stream) {
    const float* spatial = (const float*)d_in[0];   // (16,1024,768)
    const float* protos  = (const float*)d_in[1];   // (500,10,768)
    const float* rw      = (const float*)d_in[2];   // (500,10)
    const float* bias    = (const float*)d_in[3];   // (500,)
    float* out = (float*)d_out;                     // (16,500)

    unsigned short* z = (unsigned short*)d_ws;                     // 16384*768 bf16
    unsigned short* p = z + (size_t)M_ * D_;                       // 5120*768 bf16
    unsigned int* pooled = (unsigned int*)(p + (size_t)NPAD * D_); // 16*5120 u32

    prep_kernel<<<M_ / 4 + NPAD / 4, 256, 0, stream>>>(spatial, protos, z, p, pooled);
    gemm_maxpool_kernel<<<256, 512, 0, stream>>>(z, p, pooled);
    finalize_kernel<<<(B_ * C_ + 255) / 256, 256, 0, stream>>>(pooled, rw, bias, out);
}

// Round 8
// 118.171 us; speedup vs baseline: 3.4404x; 1.0588x over previous
//
#include <hip/hip_runtime.h>

// ---------------- problem constants ----------------
#define B_     16
#define L_     1024
#define D_     768
#define C_     500
#define J_     10
#define M_     (B_ * L_)        // 16384
#define NREAL  (C_ * J_)        // 5000
#define NPAD   5120             // 20 * 256
#define TM     256
#define TN     256
#define TK     64
#define KTILES (D_ / TK)        // 12

typedef __attribute__((ext_vector_type(8))) short short8;
typedef __attribute__((ext_vector_type(4))) float f32x4;

struct frag2 { short8 k[2]; };

// float <-> order-preserving uint (for atomicMax on signed floats)
static __device__ __forceinline__ unsigned f2ord(float f) {
    unsigned u = __float_as_uint(f);
    return (u & 0x80000000u) ? ~u : (u | 0x80000000u);
}
static __device__ __forceinline__ float ord2f(unsigned u) {
    return (u & 0x80000000u) ? __uint_as_float(u & 0x7fffffffu)
                             : __uint_as_float(~u);
}

// fp32 -> bf16 round-to-nearest-even
static __device__ __forceinline__ unsigned short f2bf(float f) {
    unsigned u = __float_as_uint(f);
    u += 0x7fffu + ((u >> 16) & 1u);
    return (unsigned short)(u >> 16);
}

// ---------------- kernel 1: prep = normalize both inputs + zero pooled ----------------
// blocks [0,4096): spatial rows; [4096,5376): proto rows (pad rows zeroed);
// blocks [0,80) additionally zero the pooled buffer (80*256*4 u32 = 81920).
__global__ __launch_bounds__(256) void prep_kernel(
    const float* __restrict__ spatial, const float* __restrict__ protos,
    unsigned short* __restrict__ z, unsigned short* __restrict__ pbuf,
    unsigned int* __restrict__ pooled)
{
    const int bid = blockIdx.x;
    if (bid < 80) {
        uint4 zz = {0, 0, 0, 0};
        *(uint4*)(pooled + bid * 1024 + threadIdx.x * 4) = zz;
    }

    const float* in;
    unsigned short* out;
    int row, valid;
    if (bid < 4096) { in = spatial; out = z;    row = bid * 4 + (threadIdx.x >> 6);          valid = M_; }
    else            { in = protos;  out = pbuf; row = (bid - 4096) * 4 + (threadIdx.x >> 6); valid = NREAL; }
    const int lane = threadIdx.x & 63;

    unsigned short* orow = out + (size_t)row * D_;
    if (row >= valid) {                    // zero pad rows (protos only)
        ushort4 zz = {0, 0, 0, 0};
        #pragma unroll
        for (int p = 0; p < 3; ++p)
            *(ushort4*)(orow + (p * 64 + lane) * 4) = zz;
        return;
    }

    const float4* rp = (const float4*)(in + (size_t)row * D_);
    float4 v[3];
    float s = 0.f;
    #pragma unroll
    for (int p = 0; p < 3; ++p) {
        v[p] = rp[p * 64 + lane];
        s += v[p].x * v[p].x + v[p].y * v[p].y + v[p].z * v[p].z + v[p].w * v[p].w;
    }
    #pragma unroll
    for (int off = 32; off; off >>= 1) s += __shfl_xor(s, off);
    float inv = 1.f / fmaxf(sqrtf(s), 1e-12f);
    #pragma unroll
    for (int p = 0; p < 3; ++p) {
        ushort4 o;
        o.x = f2bf(v[p].x * inv);
        o.y = f2bf(v[p].y * inv);
        o.z = f2bf(v[p].z * inv);
        o.w = f2bf(v[p].w * inv);
        *(ushort4*)(orow + (p * 64 + lane) * 4) = o;
    }
}

// ---------------- kernel 2: 256x256 8-phase GEMM + fused max-over-L ----------------
// Round-5 verified schedule (T2 swizzle + counted vmcnt + setprio, 16x16x32),
// 8 waves (2Mx4N), 128KiB LDS dbuf, 1280 blocks, XCD L2-chunked mapping.

#define MFMA(a, b, c) __builtin_amdgcn_mfma_f32_16x16x32_bf16(a, b, c, 0, 0, 0)
#define FENCE asm volatile("" ::: "memory")
#define BAR   do { FENCE; __builtin_amdgcn_s_barrier(); FENCE; } while (0)
#define VM(N) asm volatile("s_waitcnt vmcnt(" #N ")" ::: "memory")
#define PRIO1 __builtin_amdgcn_s_setprio(1)
#define PRIO0 __builtin_amdgcn_s_setprio(0)

// read a-frag pair (mi, mi+1), both kk, from buf p (offsets fold into ds imm)
#define RD_A2(dst, p, mi) do { \
    dst[0].k[0] = *(const short8*)(bA0 + (p)*32768 + (mi)*1024); \
    dst[0].k[1] = *(const short8*)(bA1 + (p)*32768 + (mi)*1024); \
    dst[1].k[0] = *(const short8*)(bA0 + (p)*32768 + ((mi)+1)*1024); \
    dst[1].k[1] = *(const short8*)(bA1 + (p)*32768 + ((mi)+1)*1024); \
} while (0)

// read all 4 b-frags, both kk, from buf p
#define RD_B4(dst, p) do { \
    _Pragma("unroll") \
    for (int ni_ = 0; ni_ < 4; ++ni_) { \
        dst[ni_].k[0] = *(const short8*)(bB0 + (p)*32768 + ni_*1024); \
        dst[ni_].k[1] = *(const short8*)(bB1 + (p)*32768 + ni_*1024); \
    } \
} while (0)

// stage one 8KB quarter (q) of A/B for buf p at k-offset k0 (elements)
#define STAGE_A(p, q, k0) __builtin_amdgcn_global_load_lds( \
    (const __attribute__((address_space(1))) void*)(Z + gA0 + (q)*64*D_ + (unsigned)(k0)), \
    (__attribute__((address_space(3))) void*)(lds + (p)*32768 + (q)*4096 + tid8), 16, 0, 0)
#define STAGE_B(p, q, k0) __builtin_amdgcn_global_load_lds( \
    (const __attribute__((address_space(1))) void*)(Pm + gB0 + (q)*64*D_ + (unsigned)(k0)), \
    (__attribute__((address_space(3))) void*)(lds + (p)*32768 + 16384 + (q)*4096 + tid8), 16, 0, 0)

// one 16-MFMA cluster: C rows 2j,2j+1 x ni 0..3 x kk 0,1
#define MMPAIR(j, S, Bv) do { \
    PRIO1; \
    _Pragma("unroll") \
    for (int ni_ = 0; ni_ < 4; ++ni_) { \
        acc[2*(j)][ni_]   = MFMA(S[0].k[0], Bv[ni_].k[0], acc[2*(j)][ni_]); \
        acc[2*(j)+1][ni_] = MFMA(S[1].k[0], Bv[ni_].k[0], acc[2*(j)+1][ni_]); \
        acc[2*(j)][ni_]   = MFMA(S[0].k[1], Bv[ni_].k[1], acc[2*(j)][ni_]); \
        acc[2*(j)+1][ni_] = MFMA(S[1].k[1], Bv[ni_].k[1], acc[2*(j)+1][ni_]); \
    } \
    PRIO0; \
} while (0)

__global__ __launch_bounds__(512, 1) void gemm_maxpool_kernel(
    const unsigned short* __restrict__ Z,   // [M_][D_] bf16 bits
    const unsigned short* __restrict__ Pm,  // [NPAD][D_] bf16 bits
    unsigned int* __restrict__ pooled)      // [B_][NPAD] ord-encoded max
{
    __shared__ unsigned short lds[65536];   // 128 KiB: buf{0,1} x (A 32K | B 32K)

    const int tid  = threadIdx.x;
    const int lane = tid & 63;
    const int wid  = tid >> 6;              // 0..7
    const int wm   = wid >> 2;              // 0..1
    const int wn   = wid & 3;               // 0..3

    // XCD L2-chunked mapping: XCD x owns bm in [8x, 8x+8), bn-outer/bm-inner
    const int xcd = (int)blockIdx.x & 7;
    const int idx = (int)blockIdx.x >> 3;   // 0..159
    const int bm  = xcd * 8 + (idx & 7);    // 0..63
    const int bn  = idx >> 3;               // 0..19
    const int row0 = bm * TM;
    const int col0 = bn * TN;

    // ---- staging addresses (T2 swizzle on global source, linear LDS dest) ----
    const int tr    = tid >> 3;                                   // row within quarter
    const int tswz  = ((tid & 7) * 16) ^ ((tr & 7) << 4);         // swizzled col byte
    const int tid8  = tid * 8;                                    // shorts (16B/thread)
    const unsigned gA0 = (unsigned)(row0 + tr) * D_ + (tswz >> 1);
    const unsigned gB0 = (unsigned)(col0 + tr) * D_ + (tswz >> 1);

    // ---- ds_read fragment base pointers (swizzled); reads add imm offsets ----
    const int l15   = lane & 15;
    const int swzl  = (lane & 7) << 4;
    const int colS0 = ((((lane >> 4) * 16)      ) ^ swzl) >> 1;
    const int colS1 = ((((lane >> 4) * 16) + 64 ) ^ swzl) >> 1;
    const unsigned short* bA0 = lds + (wm * 128 + l15) * 64 + colS0;
    const unsigned short* bA1 = lds + (wm * 128 + l15) * 64 + colS1;
    const unsigned short* bB0 = lds + 16384 + (wn * 64 + l15) * 64 + colS0;
    const unsigned short* bB1 = lds + 16384 + (wn * 64 + l15) * 64 + colS1;

    f32x4 acc[8][4] = {};
    frag2 aE[2], aO[2], bE[4], bO[4];

    // ---- prologue: stage tiles 0 (buf0) and 1 (buf1) ----
    STAGE_B(0,0,0);  STAGE_B(0,1,0);  STAGE_A(0,0,0);  STAGE_A(0,2,0);
    STAGE_B(0,2,0);  STAGE_B(0,3,0);  STAGE_A(0,1,0);  STAGE_A(0,3,0);
    STAGE_B(1,0,64); STAGE_B(1,1,64); STAGE_A(1,0,64); STAGE_A(1,2,64);
    STAGE_B(1,2,64); STAGE_B(1,3,64); STAGE_A(1,1,64); STAGE_A(1,3,64);
    VM(8);                      // tile0 landed; tile1 (8 loads) in flight
    BAR;
    RD_B4(bE, 0);               // tile0 B-all + a01
    RD_A2(aE, 0, 0);

    // ---- main loop: tiles 0..9, staging tiles 2..11 ----
    #pragma unroll 1
    for (int i = 0; i < 5; ++i) {
        const int kE = i * 128 + 128;   // k0 for tile 2i+2 (-> buf0)
        const int kO = i * 128 + 192;   // k0 for tile 2i+3 (-> buf1)
        frag2 t23[2], t45[2], t67[2];

        // ===== even tile (buf0): aE/bE =====
        RD_A2(t23, 0, 2);  STAGE_B(0, 0, kE);  STAGE_B(0, 1, kE);
        BAR; MMPAIR(0, aE, bE); BAR;

        RD_A2(t45, 0, 4);  STAGE_A(0, 0, kE);  STAGE_A(0, 2, kE);
        BAR; MMPAIR(1, t23, bE); BAR;

        RD_A2(t67, 0, 6);  STAGE_B(0, 2, kE);  STAGE_B(0, 3, kE);
        VM(6);                      // drain odd tile's 8; leave 6 in flight
        BAR; MMPAIR(2, t45, bE); BAR;

        STAGE_A(0, 1, kE);  STAGE_A(0, 3, kE);
        MMPAIR(3, t67, bE);
        RD_B4(bO, 1);  RD_A2(aO, 1, 0);         // next (odd) tile frags
        BAR;

        // ===== odd tile (buf1): aO/bO =====
        RD_A2(t23, 1, 2);  STAGE_B(1, 0, kO);  STAGE_B(1, 1, kO);
        BAR; MMPAIR(0, aO, bO); BAR;

        RD_A2(t45, 1, 4);  STAGE_A(1, 0, kO);  STAGE_A(1, 2, kO);
        BAR; MMPAIR(1, t23, bO); BAR;

        RD_A2(t67, 1, 6);  STAGE_B(1, 2, kO);  STAGE_B(1, 3, kO);
        VM(6);                      // drain even tile (2i+2)'s 8
        BAR; MMPAIR(2, t45, bO); BAR;

        STAGE_A(1, 1, kO);  STAGE_A(1, 3, kO);
        MMPAIR(3, t67, bO);
        RD_B4(bE, 0);  RD_A2(aE, 0, 0);         // tile 2i+2 frags
        BAR;
    }

    // ===== epilogue tile 10 (buf0), no staging =====
    {
        frag2 t23[2], t45[2], t67[2];
        RD_A2(t23, 0, 2);
        BAR; MMPAIR(0, aE, bE); BAR;
        RD_A2(t45, 0, 4);
        BAR; MMPAIR(1, t23, bE); BAR;
        RD_A2(t67, 0, 6);
        VM(0);                      // drain tile 11's 8 loads
        BAR; MMPAIR(2, t45, bE); BAR;
        MMPAIR(3, t67, bE);
        RD_B4(bO, 1);  RD_A2(aO, 1, 0);
        BAR;

        // ===== epilogue tile 11 (buf1) =====
        RD_A2(t23, 1, 2);
        BAR; MMPAIR(0, aO, bO); BAR;
        RD_A2(t45, 1, 4);
        BAR; MMPAIR(1, t23, bO); BAR;
        RD_A2(t67, 1, 6);
        BAR; MMPAIR(2, t45, bO); BAR;
        MMPAIR(3, t67, bO);
    }

    // ---- fused max-pool epilogue ----
    // C/D layout: col = lane&15, row = (lane>>4)*4 + reg
    const int batch = row0 >> 10;           // 256 | 1024
    #pragma unroll
    for (int ni = 0; ni < 4; ++ni) {
        float v = -3.0e38f;
        #pragma unroll
        for (int mi = 0; mi < 8; ++mi)
            v = fmaxf(v, fmaxf(fmaxf(acc[mi][ni][0], acc[mi][ni][1]),
                               fmaxf(acc[mi][ni][2], acc[mi][ni][3])));
        v = fmaxf(v, __shfl_xor(v, 16));
        v = fmaxf(v, __shfl_xor(v, 32));
        if (lane < 16) {
            int col = col0 + wn * 64 + ni * 16 + lane;
            atomicMax(&pooled[(size_t)batch * NPAD + col], f2ord(v));
        }
    }
}

// ---------------- kernel 3: finalize logits ----------------
__global__ __launch_bounds__(256) void finalize_kernel(
    const unsigned int* __restrict__ pooled,  // [B_][NPAD]
    const float* __restrict__ rw,             // [C_][J_]
    const float* __restrict__ bias,           // [C_]
    float* __restrict__ out)                  // [B_][C_]
{
    int t = blockIdx.x * 256 + threadIdx.x;
    if (t >= B_ * C_) return;
    int b = t / C_, c = t % C_;
    float s = 0.f;
    #pragma unroll
    for (int j = 0; j < J_; ++j) {
        float pv = ord2f(pooled[(size_t)b * NPAD + c * J_ + j]);
        float x  = rw[c * J_ + j];
        float w  = fmaxf(x, 0.f) + log1pf(expf(-fabsf(x)));  // softplus
        s += pv * w;
    }
    out[t] = s + bias[c];
}

// ---------------- launch ----------------
extern "C" void kernel_launch(void* const* d_in, const int* in_sizes, int n_in,
                              void* d_out, int out_size, void* d_ws, size_t ws_size,
                              hipStream_t stream) {
    const float* spatial = (const float*)d_in[0];   // (16,1024,768)
    const float* protos  = (const float*)d_in[1];   // (500,10,768)
    const float* rw      = (const float*)d_in[2];   // (500,10)
    const float* bias    = (const float*)d_in[3];   // (500,)
    float* out = (float*)d_out;                     // (16,500)

    unsigned short* z = (unsigned short*)d_ws;                     // 16384*768 bf16
    unsigned short* p = z + (size_t)M_ * D_;                       // 5120*768 bf16
    unsigned int* pooled = (unsigned int*)(p + (size_t)NPAD * D_); // 16*5120 u32

    prep_kernel<<<M_ / 4 + NPAD / 4, 256, 0, stream>>>(spatial, protos, z, p, pooled);
    gemm_maxpool_kernel<<<(M_ / TM) * (NPAD / TN), 512, 0, stream>>>(z, p, pooled);
    finalize_kernel<<<(B_ * C_ + 255) / 256, 256, 0, stream>>>(pooled, rw, bias, out);
}